// Round 4
// baseline (715.825 us; speedup 1.0000x reference)
//
#include <hip/hip_runtime.h>
#include <math.h>

// Problem constants (match reference file)
#define N_NODES 100000
#define N_EDGES 1600000
#define TOT_EDGES (N_EDGES + N_NODES)   // with self-loops
#define HID 64
#define NB 391                          // node buckets of 256 (100000 >> 8 -> 0..390)

// ---------------------------------------------------------------------------
// Bucketed CSR build (sorted by dst).
// ---------------------------------------------------------------------------

__global__ void k_bin_count(const int* __restrict__ dst, int* __restrict__ bcnt) {
    __shared__ int hist[NB];
    for (int t = threadIdx.x; t < NB; t += blockDim.x) hist[t] = 0;
    __syncthreads();
    int stride = gridDim.x * blockDim.x;
    for (int e = blockIdx.x * blockDim.x + threadIdx.x; e < N_EDGES; e += stride)
        atomicAdd(&hist[dst[e] >> 8], 1);
    __syncthreads();
    for (int t = threadIdx.x; t < NB; t += blockDim.x)
        if (hist[t]) atomicAdd(&bcnt[t], hist[t]);
}

__global__ void k_bucket_scan(const int* __restrict__ bcnt, int* __restrict__ boff,
                              int* __restrict__ bcur) {
    __shared__ int lds[512];
    int t = threadIdx.x;
    int v = (t < NB) ? bcnt[t] : 0;
    lds[t] = v;
    __syncthreads();
    for (int off = 1; off < 512; off <<= 1) {
        int add = (t >= off) ? lds[t - off] : 0;
        __syncthreads();
        lds[t] += add;
        __syncthreads();
    }
    if (t < NB) { int excl = lds[t] - v; boff[t] = excl; bcur[t] = excl; }
    if (t == 0) boff[NB] = N_EDGES;
}

__global__ void k_bin_scatter(const int* __restrict__ src, const int* __restrict__ dst,
                              int* __restrict__ bcur, int2* __restrict__ binned) {
    __shared__ int hist[NB];
    __shared__ int base[NB];
    for (int t = threadIdx.x; t < NB; t += blockDim.x) hist[t] = 0;
    __syncthreads();
    int stride = gridDim.x * blockDim.x;
    int gid = blockIdx.x * blockDim.x + threadIdx.x;
    for (int e = gid; e < N_EDGES; e += stride)
        atomicAdd(&hist[dst[e] >> 8], 1);
    __syncthreads();
    for (int t = threadIdx.x; t < NB; t += blockDim.x) {
        int h = hist[t];
        base[t] = h ? atomicAdd(&bcur[t], h) : 0;
        hist[t] = 0;
    }
    __syncthreads();
    for (int e = gid; e < N_EDGES; e += stride) {
        int d = dst[e];
        int bkt = d >> 8;
        int off = base[bkt] + atomicAdd(&hist[bkt], 1);
        binned[off] = make_int2(src[e], d);
    }
}

__global__ void k_node_count(const int2* __restrict__ binned, const int* __restrict__ boff,
                             int* __restrict__ cnt) {
    __shared__ int c[256];
    int b = blockIdx.x;
    int n0 = b << 8;
    int nn = min(256, N_NODES - n0);
    c[threadIdx.x] = 1;  // self-loop
    __syncthreads();
    int e0 = boff[b], e1 = boff[b + 1];
    for (int i = e0 + threadIdx.x; i < e1; i += blockDim.x)
        atomicAdd(&c[binned[i].y & 255], 1);
    __syncthreads();
    if (threadIdx.x < nn) cnt[n0 + threadIdx.x] = c[threadIdx.x];
}

__global__ void k_csr_scatter(const int2* __restrict__ binned, const int* __restrict__ boff,
                              const int* __restrict__ rowoff, int* __restrict__ srcs) {
    __shared__ int cur[256];
    int b = blockIdx.x;
    int n0 = b << 8;
    int nn = min(256, N_NODES - n0);
    if (threadIdx.x < nn) cur[threadIdx.x] = rowoff[n0 + threadIdx.x];
    __syncthreads();
    int e0 = boff[b], e1 = boff[b + 1];
    for (int i = e0 + threadIdx.x; i < e1; i += blockDim.x) {
        int2 p = binned[i];
        int pos = atomicAdd(&cur[p.y & 255], 1);
        srcs[pos] = p.x;
    }
    __syncthreads();
    if (threadIdx.x < nn) srcs[cur[threadIdx.x]] = n0 + threadIdx.x;  // self-loop (last slot)
}

// ---------------------------------------------------------------------------
// Node scans
// ---------------------------------------------------------------------------

__global__ void k_scan1(const int* __restrict__ cnt, int* __restrict__ partial) {
    __shared__ int lds[256];
    int i = blockIdx.x * 256 + threadIdx.x;
    int v = (i < N_NODES) ? cnt[i] : 0;
    lds[threadIdx.x] = v;
    __syncthreads();
    for (int s = 128; s > 0; s >>= 1) {
        if (threadIdx.x < s) lds[threadIdx.x] += lds[threadIdx.x + s];
        __syncthreads();
    }
    if (threadIdx.x == 0) partial[blockIdx.x] = lds[0];
}

__global__ void k_scan2(int* __restrict__ partial, int nb) {
    __shared__ int lds[512];
    int t = threadIdx.x;
    int v = (t < nb) ? partial[t] : 0;
    lds[t] = v;
    __syncthreads();
    for (int off = 1; off < 512; off <<= 1) {
        int add = (t >= off) ? lds[t - off] : 0;
        __syncthreads();
        lds[t] += add;
        __syncthreads();
    }
    if (t < nb) partial[t] = lds[t] - v;  // exclusive
}

__global__ void k_scan3(const int* __restrict__ cnt, const int* __restrict__ partial,
                        int* __restrict__ rowoff, float* __restrict__ dinv,
                        const float* __restrict__ x, float* __restrict__ xs) {
    __shared__ int lds[256];
    int i = blockIdx.x * 256 + threadIdx.x;
    int v = (i < N_NODES) ? cnt[i] : 0;
    lds[threadIdx.x] = v;
    __syncthreads();
    for (int off = 1; off < 256; off <<= 1) {
        int add = (threadIdx.x >= off) ? lds[threadIdx.x - off] : 0;
        __syncthreads();
        lds[threadIdx.x] += add;
        __syncthreads();
    }
    if (i < N_NODES) {
        int excl = partial[blockIdx.x] + lds[threadIdx.x] - v;
        rowoff[i] = excl;
        float di = rsqrtf((float)v);  // deg >= 1 always (self-loop)
        dinv[i] = di;
        float4 xv = ((const float4*)x)[i];
        xv.x *= di; xv.y *= di; xv.z *= di; xv.w *= di;
        ((float4*)xs)[i] = xv;
        if (i == N_NODES - 1) rowoff[N_NODES] = excl + v;
    }
}

// ---------------------------------------------------------------------------
// GCN1 aggregation in 4-channel input space.
// ---------------------------------------------------------------------------
__global__ void k_agg_x(const int* __restrict__ rowoff, const int* __restrict__ srcs,
                        const float* __restrict__ xs, const float* __restrict__ dinv,
                        float* __restrict__ aggx) {
    int lane = threadIdx.x & 63;
    int w    = threadIdx.x >> 6;
    int g    = lane >> 4;   // node within wave
    int q    = lane & 15;   // edge slot
    int i    = blockIdx.x * 16 + w * 4 + g;
    int b = rowoff[i], en = rowoff[i + 1];
    float4 acc = {0.f, 0.f, 0.f, 0.f};
    for (int p = b + q; p < en; p += 16) {
        int s = srcs[p];
        float4 v = ((const float4*)xs)[s];
        acc.x += v.x; acc.y += v.y; acc.z += v.z; acc.w += v.w;
    }
#pragma unroll
    for (int mask = 1; mask <= 8; mask <<= 1) {
        acc.x += __shfl_xor(acc.x, mask);
        acc.y += __shfl_xor(acc.y, mask);
        acc.z += __shfl_xor(acc.z, mask);
        acc.w += __shfl_xor(acc.w, mask);
    }
    if (q == 0) {
        float di = dinv[i];
        acc.x *= di; acc.y *= di; acc.z *= di; acc.w *= di;
        ((float4*)aggx)[i] = acc;
    }
}

// ---------------------------------------------------------------------------
// h1 = relu(aggx @ W1 + b1); hl = h1 @ Wl; hr = h1 @ Wr
// Register-tiled GEMM: block = 256 threads = 64 nodes.
// Phase 1: h1 tile -> LDS [64][64].  Phase 2: thread owns (channel=lane,
// 16 nodes), k-loop step 4: 8 weight loads serve 128 FMAs; h1 via uniform
// ds_read_b128 broadcast.  Grid: ceil(N/64) blocks.
// ---------------------------------------------------------------------------
__global__ void __launch_bounds__(256) k_hlhr(
        const float* __restrict__ aggx, const float* __restrict__ W1,
        const float* __restrict__ b1, const float* __restrict__ Wl,
        const float* __restrict__ Wr, float* __restrict__ hl,
        float* __restrict__ hr) {
    __shared__ float h1[64 * HID];
    int lane = threadIdx.x & 63;
    int w    = threadIdx.x >> 6;
    int n0   = blockIdx.x * 64;
    // phase 1: h1 for 64 nodes (wave w handles nodes n = 4j + w)
    float w10 = W1[0 * HID + lane], w11 = W1[1 * HID + lane];
    float w12 = W1[2 * HID + lane], w13 = W1[3 * HID + lane];
    float bb  = b1[lane];
#pragma unroll
    for (int j = 0; j < 16; ++j) {
        int n  = j * 4 + w;
        int gn = n0 + n;
        float h = 0.f;
        if (gn < N_NODES) {
            float4 a = ((const float4*)aggx)[gn];
            h = fmaxf(a.x * w10 + a.y * w11 + a.z * w12 + a.w * w13 + bb, 0.f);
        }
        h1[n * HID + lane] = h;
    }
    __syncthreads();
    // phase 2
    float al[16], ar[16];
#pragma unroll
    for (int j = 0; j < 16; ++j) { al[j] = 0.f; ar[j] = 0.f; }
#pragma unroll
    for (int k0 = 0; k0 < 16; ++k0) {
        float wl0 = Wl[(k0 * 4 + 0) * HID + lane];
        float wl1 = Wl[(k0 * 4 + 1) * HID + lane];
        float wl2 = Wl[(k0 * 4 + 2) * HID + lane];
        float wl3 = Wl[(k0 * 4 + 3) * HID + lane];
        float wr0 = Wr[(k0 * 4 + 0) * HID + lane];
        float wr1 = Wr[(k0 * 4 + 1) * HID + lane];
        float wr2 = Wr[(k0 * 4 + 2) * HID + lane];
        float wr3 = Wr[(k0 * 4 + 3) * HID + lane];
#pragma unroll
        for (int j = 0; j < 16; ++j) {
            const float4 hv = *(const float4*)(&h1[(j * 4 + w) * HID + k0 * 4]);
            al[j] += hv.x * wl0 + hv.y * wl1 + hv.z * wl2 + hv.w * wl3;
            ar[j] += hv.x * wr0 + hv.y * wr1 + hv.z * wr2 + hv.w * wr3;
        }
    }
#pragma unroll
    for (int j = 0; j < 16; ++j) {
        int gn = n0 + j * 4 + w;
        if (gn < N_NODES) {
            hl[(size_t)gn * HID + lane] = al[j];
            hr[(size_t)gn * HID + lane] = ar[j];
        }
    }
}

// ---------------------------------------------------------------------------
// GATv2 online softmax, 2x unrolled: 8 row-gathers in flight per wave.
// ---------------------------------------------------------------------------
__global__ void k_gat(const int* __restrict__ rowoff, const int* __restrict__ srcs,
                      const float* __restrict__ hl, const float* __restrict__ hr,
                      const float* __restrict__ att, const float* __restrict__ gat_b,
                      const float* __restrict__ dinv, float* __restrict__ s2) {
    int lane = threadIdx.x & 63;
    int w    = threadIdx.x >> 6;
    int g    = lane >> 4;
    int q    = lane & 15;
    int c0   = q * 4;
    int i    = blockIdx.x * 4 + w;
    const float4 hri = *(const float4*)(hr + (size_t)i * HID + c0);
    const float4 a4  = *(const float4*)(att + c0);
    float  m = -1e30f, denom = 0.f;
    float4 acc = {0.f, 0.f, 0.f, 0.f};
    int b = rowoff[i], en = rowoff[i + 1];
    int p = b + g;
    for (; p + 4 < en; p += 8) {
        int s0 = srcs[p];
        int s1 = srcs[p + 4];
        const float4 v0 = *(const float4*)(hl + (size_t)s0 * HID + c0);
        const float4 v1 = *(const float4*)(hl + (size_t)s1 * HID + c0);
        float ex0, ey0, ez0, ew0, ex1, ey1, ez1, ew1;
        ex0 = v0.x + hri.x; ey0 = v0.y + hri.y; ez0 = v0.z + hri.z; ew0 = v0.w + hri.w;
        ex1 = v1.x + hri.x; ey1 = v1.y + hri.y; ez1 = v1.z + hri.z; ew1 = v1.w + hri.w;
        ex0 = (ex0 > 0.f) ? ex0 : 0.2f * ex0; ey0 = (ey0 > 0.f) ? ey0 : 0.2f * ey0;
        ez0 = (ez0 > 0.f) ? ez0 : 0.2f * ez0; ew0 = (ew0 > 0.f) ? ew0 : 0.2f * ew0;
        ex1 = (ex1 > 0.f) ? ex1 : 0.2f * ex1; ey1 = (ey1 > 0.f) ? ey1 : 0.2f * ey1;
        ez1 = (ez1 > 0.f) ? ez1 : 0.2f * ez1; ew1 = (ew1 > 0.f) ? ew1 : 0.2f * ew1;
        float t0 = ex0 * a4.x + ey0 * a4.y + ez0 * a4.z + ew0 * a4.w;
        float t1 = ex1 * a4.x + ey1 * a4.y + ez1 * a4.z + ew1 * a4.w;
        t0 += __shfl_xor(t0, 1); t1 += __shfl_xor(t1, 1);
        t0 += __shfl_xor(t0, 2); t1 += __shfl_xor(t1, 2);
        t0 += __shfl_xor(t0, 4); t1 += __shfl_xor(t1, 4);
        float nm = fmaxf(m, t0);
        float sc = __expf(m - nm);
        float ex = __expf(t0 - nm);
        denom = denom * sc + ex;
        acc.x = acc.x * sc + ex * v0.x;
        acc.y = acc.y * sc + ex * v0.y;
        acc.z = acc.z * sc + ex * v0.z;
        acc.w = acc.w * sc + ex * v0.w;
        m = nm;
        nm = fmaxf(m, t1);
        sc = __expf(m - nm);
        ex = __expf(t1 - nm);
        denom = denom * sc + ex;
        acc.x = acc.x * sc + ex * v1.x;
        acc.y = acc.y * sc + ex * v1.y;
        acc.z = acc.z * sc + ex * v1.z;
        acc.w = acc.w * sc + ex * v1.w;
        m = nm;
    }
    if (p < en) {
        int s = srcs[p];
        const float4 v = *(const float4*)(hl + (size_t)s * HID + c0);
        float ex0 = v.x + hri.x, ey0 = v.y + hri.y, ez0 = v.z + hri.z, ew0 = v.w + hri.w;
        ex0 = (ex0 > 0.f) ? ex0 : 0.2f * ex0; ey0 = (ey0 > 0.f) ? ey0 : 0.2f * ey0;
        ez0 = (ez0 > 0.f) ? ez0 : 0.2f * ez0; ew0 = (ew0 > 0.f) ? ew0 : 0.2f * ew0;
        float t0 = ex0 * a4.x + ey0 * a4.y + ez0 * a4.z + ew0 * a4.w;
        t0 += __shfl_xor(t0, 1);
        t0 += __shfl_xor(t0, 2);
        t0 += __shfl_xor(t0, 4);
        float nm = fmaxf(m, t0);
        float sc = __expf(m - nm);
        float ex = __expf(t0 - nm);
        denom = denom * sc + ex;
        acc.x = acc.x * sc + ex * v.x;
        acc.y = acc.y * sc + ex * v.y;
        acc.z = acc.z * sc + ex * v.z;
        acc.w = acc.w * sc + ex * v.w;
        m = nm;
    }
#pragma unroll
    for (int mask = 16; mask <= 32; mask <<= 1) {
        float m2 = __shfl_xor(m, mask);
        float d2 = __shfl_xor(denom, mask);
        float ax = __shfl_xor(acc.x, mask);
        float ay = __shfl_xor(acc.y, mask);
        float az = __shfl_xor(acc.z, mask);
        float aw = __shfl_xor(acc.w, mask);
        float nm = fmaxf(m, m2);
        float sa = __expf(m - nm);
        float sb = __expf(m2 - nm);
        denom = denom * sa + d2 * sb;
        acc.x = acc.x * sa + ax * sb;
        acc.y = acc.y * sa + ay * sb;
        acc.z = acc.z * sa + az * sb;
        acc.w = acc.w * sa + aw * sb;
        m = nm;
    }
    float inv = 1.f / (denom + 1e-16f);
    const float4 gb = *(const float4*)(gat_b + c0);
    float di = dinv[i];
    float4 o;
    o.x = fmaxf(acc.x * inv + gb.x, 0.f) * di;
    o.y = fmaxf(acc.y * inv + gb.y, 0.f) * di;
    o.z = fmaxf(acc.z * inv + gb.z, 0.f) * di;
    o.w = fmaxf(acc.w * inv + gb.w, 0.f) * di;
    if (g == 0) *(float4*)(s2 + (size_t)i * HID + c0) = o;
}

// ---------------------------------------------------------------------------
// GCN2 aggregation + transform + bias + relu + final linear, all fused.
// ---------------------------------------------------------------------------
__global__ void k_agg2_out(const int* __restrict__ rowoff, const int* __restrict__ srcs,
                           const float* __restrict__ s2, const float* __restrict__ dinv,
                           const float* __restrict__ W2, const float* __restrict__ b2,
                           const float* __restrict__ out_w, const float* __restrict__ out_b,
                           float* __restrict__ out) {
    __shared__ float lds[4][HID];
    int lane = threadIdx.x & 63;
    int w    = threadIdx.x >> 6;
    int g    = lane >> 4;
    int q    = lane & 15;
    int c0   = q * 4;
    int i    = blockIdx.x * 4 + w;
    int b = rowoff[i], en = rowoff[i + 1];
    float4 acc = {0.f, 0.f, 0.f, 0.f};
    int p = b + g;
    for (; p + 4 < en; p += 8) {
        int s0 = srcs[p];
        int s1 = srcs[p + 4];
        const float4 v0 = *(const float4*)(s2 + (size_t)s0 * HID + c0);
        const float4 v1 = *(const float4*)(s2 + (size_t)s1 * HID + c0);
        acc.x += v0.x + v1.x; acc.y += v0.y + v1.y;
        acc.z += v0.z + v1.z; acc.w += v0.w + v1.w;
    }
    if (p < en) {
        int s = srcs[p];
        const float4 v = *(const float4*)(s2 + (size_t)s * HID + c0);
        acc.x += v.x; acc.y += v.y; acc.z += v.z; acc.w += v.w;
    }
#pragma unroll
    for (int mask = 16; mask <= 32; mask <<= 1) {
        acc.x += __shfl_xor(acc.x, mask);
        acc.y += __shfl_xor(acc.y, mask);
        acc.z += __shfl_xor(acc.z, mask);
        acc.w += __shfl_xor(acc.w, mask);
    }
    if (g == 0) {
        float di = dinv[i];
        acc.x *= di; acc.y *= di; acc.z *= di; acc.w *= di;
        *(float4*)(&lds[w][c0]) = acc;
    }
    __syncthreads();
    float z = 0.f;
    const float4* row = (const float4*)lds[w];
#pragma unroll
    for (int j = 0; j < 16; ++j) {
        float4 h4 = row[j];
        z += h4.x * W2[(4 * j + 0) * HID + lane];
        z += h4.y * W2[(4 * j + 1) * HID + lane];
        z += h4.z * W2[(4 * j + 2) * HID + lane];
        z += h4.w * W2[(4 * j + 3) * HID + lane];
    }
    z = fmaxf(z + b2[lane], 0.f);
    float y = z * out_w[lane];  // out_w is (64,1) flat
    y += __shfl_xor(y, 32);
    y += __shfl_xor(y, 16);
    y += __shfl_xor(y, 8);
    y += __shfl_xor(y, 4);
    y += __shfl_xor(y, 2);
    y += __shfl_xor(y, 1);
    if (lane == 0) out[i] = y + out_b[0];
}

// ---------------------------------------------------------------------------

extern "C" void kernel_launch(void* const* d_in, const int* in_sizes, int n_in,
                              void* d_out, int out_size, void* d_ws, size_t ws_size,
                              hipStream_t stream) {
    const float* x   = (const float*)d_in[0];
    const int*   ei  = (const int*)d_in[1];
    const int*   src = ei;
    const int*   dst = ei + N_EDGES;
    const float* W1  = (const float*)d_in[2];
    const float* b1  = (const float*)d_in[3];
    const float* Wl  = (const float*)d_in[4];
    const float* Wr  = (const float*)d_in[5];
    const float* att = (const float*)d_in[6];
    const float* gb  = (const float*)d_in[7];
    const float* W2  = (const float*)d_in[8];
    const float* b2  = (const float*)d_in[9];
    const float* ow  = (const float*)d_in[10];
    const float* ob  = (const float*)d_in[11];
    float* out = (float*)d_out;

    // workspace layout (256B-aligned regions)
    char* ws = (char*)d_ws;
    size_t o = 0;
    auto alloc = [&](size_t bytes) { size_t r = o; o = (o + bytes + 255) & ~(size_t)255; return r; };
    int*   cnt     = (int*)  (ws + alloc((size_t)N_NODES * 4));
    int*   rowoff  = (int*)  (ws + alloc((size_t)(N_NODES + 1) * 4));
    int*   partial = (int*)  (ws + alloc(512 * 4));
    int*   bcnt    = (int*)  (ws + alloc((size_t)NB * 4));
    int*   boff    = (int*)  (ws + alloc((size_t)(NB + 1) * 4));
    int*   bcur    = (int*)  (ws + alloc((size_t)NB * 4));
    float* dinv    = (float*)(ws + alloc((size_t)N_NODES * 4));
    float* xs      = (float*)(ws + alloc((size_t)N_NODES * 4 * 4));
    float* aggx    = (float*)(ws + alloc((size_t)N_NODES * 4 * 4));
    int2*  binned  = (int2*) (ws + alloc((size_t)N_EDGES * 8));
    int*   srcs    = (int*)  (ws + alloc((size_t)TOT_EDGES * 4));
    float* hl      = (float*)(ws + alloc((size_t)N_NODES * HID * 4));
    float* hr      = (float*)(ws + alloc((size_t)N_NODES * HID * 4));
    float* s2      = (float*)(ws + alloc((size_t)N_NODES * HID * 4));
    (void)ws_size; (void)n_in; (void)in_sizes; (void)out_size;

    const int nbN   = (N_NODES + 255) / 256;      // 391
    const int nbW   = N_NODES / 4;                // 25000 (wave-per-node kernels, exact)
    const int nbW16 = N_NODES / 16;               // 6250  (4 nodes/wave kernels, exact)
    const int nbG   = (N_NODES + 63) / 64;        // 1563  (tiled GEMM blocks)

    hipMemsetAsync(bcnt, 0, (size_t)NB * 4, stream);
    k_bin_count<<<128, 1024, 0, stream>>>(dst, bcnt);
    k_bucket_scan<<<1, 512, 0, stream>>>(bcnt, boff, bcur);
    k_bin_scatter<<<128, 1024, 0, stream>>>(src, dst, bcur, binned);
    k_node_count<<<NB, 256, 0, stream>>>(binned, boff, cnt);
    k_scan1<<<nbN, 256, 0, stream>>>(cnt, partial);
    k_scan2<<<1, 512, 0, stream>>>(partial, nbN);
    k_scan3<<<nbN, 256, 0, stream>>>(cnt, partial, rowoff, dinv, x, xs);
    k_csr_scatter<<<NB, 256, 0, stream>>>(binned, boff, rowoff, srcs);
    k_agg_x<<<nbW16, 256, 0, stream>>>(rowoff, srcs, xs, dinv, aggx);
    k_hlhr<<<nbG, 256, 0, stream>>>(aggx, W1, b1, Wl, Wr, hl, hr);
    k_gat<<<nbW, 256, 0, stream>>>(rowoff, srcs, hl, hr, att, gb, dinv, s2);
    k_agg2_out<<<nbW, 256, 0, stream>>>(rowoff, srcs, s2, dinv, W2, b2, ow, ob, out);
}

// Round 5
// 276.948 us; speedup vs baseline: 2.5847x; 2.5847x over previous
//
#include <hip/hip_runtime.h>
#include <math.h>

// Problem constants (match reference file)
#define N_NODES 100000
#define N_EDGES 1600000
#define TOT_EDGES (N_EDGES + N_NODES)   // with self-loops
#define HID 64
#define NB 391                          // node buckets of 256 (100000 >> 8 -> 0..390)

// ---------------------------------------------------------------------------
// Bucketed CSR build (sorted by dst).
// ---------------------------------------------------------------------------

__global__ void k_bin_count(const int* __restrict__ dst, int* __restrict__ bcnt) {
    __shared__ int hist[NB];
    for (int t = threadIdx.x; t < NB; t += blockDim.x) hist[t] = 0;
    __syncthreads();
    int stride = gridDim.x * blockDim.x;
    for (int e = blockIdx.x * blockDim.x + threadIdx.x; e < N_EDGES; e += stride)
        atomicAdd(&hist[dst[e] >> 8], 1);
    __syncthreads();
    for (int t = threadIdx.x; t < NB; t += blockDim.x)
        if (hist[t]) atomicAdd(&bcnt[t], hist[t]);
}

__global__ void k_bucket_scan(const int* __restrict__ bcnt, int* __restrict__ boff,
                              int* __restrict__ bcur) {
    __shared__ int lds[512];
    int t = threadIdx.x;
    int v = (t < NB) ? bcnt[t] : 0;
    lds[t] = v;
    __syncthreads();
    for (int off = 1; off < 512; off <<= 1) {
        int add = (t >= off) ? lds[t - off] : 0;
        __syncthreads();
        lds[t] += add;
        __syncthreads();
    }
    if (t < NB) { int excl = lds[t] - v; boff[t] = excl; bcur[t] = excl; }
    if (t == 0) boff[NB] = N_EDGES;
}

__global__ void k_bin_scatter(const int* __restrict__ src, const int* __restrict__ dst,
                              int* __restrict__ bcur, int2* __restrict__ binned) {
    __shared__ int hist[NB];
    __shared__ int base[NB];
    for (int t = threadIdx.x; t < NB; t += blockDim.x) hist[t] = 0;
    __syncthreads();
    int stride = gridDim.x * blockDim.x;
    int gid = blockIdx.x * blockDim.x + threadIdx.x;
    for (int e = gid; e < N_EDGES; e += stride)
        atomicAdd(&hist[dst[e] >> 8], 1);
    __syncthreads();
    for (int t = threadIdx.x; t < NB; t += blockDim.x) {
        int h = hist[t];
        base[t] = h ? atomicAdd(&bcur[t], h) : 0;
        hist[t] = 0;
    }
    __syncthreads();
    for (int e = gid; e < N_EDGES; e += stride) {
        int d = dst[e];
        int bkt = d >> 8;
        int off = base[bkt] + atomicAdd(&hist[bkt], 1);
        binned[off] = make_int2(src[e], d);
    }
}

__global__ void k_node_count(const int2* __restrict__ binned, const int* __restrict__ boff,
                             int* __restrict__ cnt) {
    __shared__ int c[256];
    int b = blockIdx.x;
    int n0 = b << 8;
    int nn = min(256, N_NODES - n0);
    c[threadIdx.x] = 1;  // self-loop
    __syncthreads();
    int e0 = boff[b], e1 = boff[b + 1];
    for (int i = e0 + threadIdx.x; i < e1; i += blockDim.x)
        atomicAdd(&c[binned[i].y & 255], 1);
    __syncthreads();
    if (threadIdx.x < nn) cnt[n0 + threadIdx.x] = c[threadIdx.x];
}

__global__ void k_csr_scatter(const int2* __restrict__ binned, const int* __restrict__ boff,
                              const int* __restrict__ rowoff, int* __restrict__ srcs) {
    __shared__ int cur[256];
    int b = blockIdx.x;
    int n0 = b << 8;
    int nn = min(256, N_NODES - n0);
    if (threadIdx.x < nn) cur[threadIdx.x] = rowoff[n0 + threadIdx.x];
    __syncthreads();
    int e0 = boff[b], e1 = boff[b + 1];
    for (int i = e0 + threadIdx.x; i < e1; i += blockDim.x) {
        int2 p = binned[i];
        int pos = atomicAdd(&cur[p.y & 255], 1);
        srcs[pos] = p.x;
    }
    __syncthreads();
    if (threadIdx.x < nn) srcs[cur[threadIdx.x]] = n0 + threadIdx.x;  // self-loop (last slot)
}

// ---------------------------------------------------------------------------
// Node scans
// ---------------------------------------------------------------------------

__global__ void k_scan1(const int* __restrict__ cnt, int* __restrict__ partial) {
    __shared__ int lds[256];
    int i = blockIdx.x * 256 + threadIdx.x;
    int v = (i < N_NODES) ? cnt[i] : 0;
    lds[threadIdx.x] = v;
    __syncthreads();
    for (int s = 128; s > 0; s >>= 1) {
        if (threadIdx.x < s) lds[threadIdx.x] += lds[threadIdx.x + s];
        __syncthreads();
    }
    if (threadIdx.x == 0) partial[blockIdx.x] = lds[0];
}

__global__ void k_scan2(int* __restrict__ partial, int nb) {
    __shared__ int lds[512];
    int t = threadIdx.x;
    int v = (t < nb) ? partial[t] : 0;
    lds[t] = v;
    __syncthreads();
    for (int off = 1; off < 512; off <<= 1) {
        int add = (t >= off) ? lds[t - off] : 0;
        __syncthreads();
        lds[t] += add;
        __syncthreads();
    }
    if (t < nb) partial[t] = lds[t] - v;  // exclusive
}

__global__ void k_scan3(const int* __restrict__ cnt, const int* __restrict__ partial,
                        int* __restrict__ rowoff, float* __restrict__ dinv,
                        const float* __restrict__ x, float* __restrict__ xs) {
    __shared__ int lds[256];
    int i = blockIdx.x * 256 + threadIdx.x;
    int v = (i < N_NODES) ? cnt[i] : 0;
    lds[threadIdx.x] = v;
    __syncthreads();
    for (int off = 1; off < 256; off <<= 1) {
        int add = (threadIdx.x >= off) ? lds[threadIdx.x - off] : 0;
        __syncthreads();
        lds[threadIdx.x] += add;
        __syncthreads();
    }
    if (i < N_NODES) {
        int excl = partial[blockIdx.x] + lds[threadIdx.x] - v;
        rowoff[i] = excl;
        float di = rsqrtf((float)v);  // deg >= 1 always (self-loop)
        dinv[i] = di;
        float4 xv = ((const float4*)x)[i];
        xv.x *= di; xv.y *= di; xv.z *= di; xv.w *= di;
        ((float4*)xs)[i] = xv;
        if (i == N_NODES - 1) rowoff[N_NODES] = excl + v;
    }
}

// ---------------------------------------------------------------------------
// GCN1 aggregation in 4-channel input space.
// ---------------------------------------------------------------------------
__global__ void k_agg_x(const int* __restrict__ rowoff, const int* __restrict__ srcs,
                        const float* __restrict__ xs, const float* __restrict__ dinv,
                        float* __restrict__ aggx) {
    int lane = threadIdx.x & 63;
    int w    = threadIdx.x >> 6;
    int g    = lane >> 4;   // node within wave
    int q    = lane & 15;   // edge slot
    int i    = blockIdx.x * 16 + w * 4 + g;
    int b = rowoff[i], en = rowoff[i + 1];
    float4 acc = {0.f, 0.f, 0.f, 0.f};
    for (int p = b + q; p < en; p += 16) {
        int s = srcs[p];
        float4 v = ((const float4*)xs)[s];
        acc.x += v.x; acc.y += v.y; acc.z += v.z; acc.w += v.w;
    }
#pragma unroll
    for (int mask = 1; mask <= 8; mask <<= 1) {
        acc.x += __shfl_xor(acc.x, mask);
        acc.y += __shfl_xor(acc.y, mask);
        acc.z += __shfl_xor(acc.z, mask);
        acc.w += __shfl_xor(acc.w, mask);
    }
    if (q == 0) {
        float di = dinv[i];
        acc.x *= di; acc.y *= di; acc.z *= di; acc.w *= di;
        ((float4*)aggx)[i] = acc;
    }
}

// ---------------------------------------------------------------------------
// h1 = relu(aggx @ W1 + b1); hl = h1 @ Wl; hr = h1 @ Wr
// Register-tiled GEMM, tile sized to avoid spills:
//   block = 256 threads = 32 nodes (3125 blocks exactly, no tail).
//   Phase 1: h1 tile -> LDS [32][64] (8 KB).
//   Phase 2: thread owns channel=lane x 8 nodes (al[8]+ar[8]=16 acc VGPRs);
//            k-loop 16 steps (unroll 2): 8 weight loads serve 64 FMAs;
//            h1 read as wave-uniform ds_read_b128 broadcast (conflict-free).
// ---------------------------------------------------------------------------
__global__ void __launch_bounds__(256) k_hlhr(
        const float* __restrict__ aggx, const float* __restrict__ W1,
        const float* __restrict__ b1, const float* __restrict__ Wl,
        const float* __restrict__ Wr, float* __restrict__ hl,
        float* __restrict__ hr) {
    __shared__ float h1[32 * HID];
    int lane = threadIdx.x & 63;
    int w    = threadIdx.x >> 6;
    int n0   = blockIdx.x * 32;
    // phase 1: wave w computes h1 rows n = w*8 .. w*8+7
    float w10 = W1[0 * HID + lane], w11 = W1[1 * HID + lane];
    float w12 = W1[2 * HID + lane], w13 = W1[3 * HID + lane];
    float bb  = b1[lane];
#pragma unroll
    for (int j = 0; j < 8; ++j) {
        int n = w * 8 + j;
        float4 a = ((const float4*)aggx)[n0 + n];
        float h = fmaxf(a.x * w10 + a.y * w11 + a.z * w12 + a.w * w13 + bb, 0.f);
        h1[n * HID + lane] = h;
    }
    __syncthreads();
    // phase 2: 8 nodes per thread, k in chunks of 4
    float al[8], ar[8];
#pragma unroll
    for (int j = 0; j < 8; ++j) { al[j] = 0.f; ar[j] = 0.f; }
#pragma unroll 2
    for (int k0 = 0; k0 < 16; ++k0) {
        float wl0 = Wl[(k0 * 4 + 0) * HID + lane];
        float wl1 = Wl[(k0 * 4 + 1) * HID + lane];
        float wl2 = Wl[(k0 * 4 + 2) * HID + lane];
        float wl3 = Wl[(k0 * 4 + 3) * HID + lane];
        float wr0 = Wr[(k0 * 4 + 0) * HID + lane];
        float wr1 = Wr[(k0 * 4 + 1) * HID + lane];
        float wr2 = Wr[(k0 * 4 + 2) * HID + lane];
        float wr3 = Wr[(k0 * 4 + 3) * HID + lane];
#pragma unroll
        for (int j = 0; j < 8; ++j) {
            const float4 hv = *(const float4*)(&h1[(w * 8 + j) * HID + k0 * 4]);
            al[j] += hv.x * wl0 + hv.y * wl1 + hv.z * wl2 + hv.w * wl3;
            ar[j] += hv.x * wr0 + hv.y * wr1 + hv.z * wr2 + hv.w * wr3;
        }
    }
#pragma unroll
    for (int j = 0; j < 8; ++j) {
        int gn = n0 + w * 8 + j;
        hl[(size_t)gn * HID + lane] = al[j];
        hr[(size_t)gn * HID + lane] = ar[j];
    }
}

// ---------------------------------------------------------------------------
// GATv2 online softmax, 2x unrolled: 8 row-gathers in flight per wave.
// ---------------------------------------------------------------------------
__global__ void k_gat(const int* __restrict__ rowoff, const int* __restrict__ srcs,
                      const float* __restrict__ hl, const float* __restrict__ hr,
                      const float* __restrict__ att, const float* __restrict__ gat_b,
                      const float* __restrict__ dinv, float* __restrict__ s2) {
    int lane = threadIdx.x & 63;
    int w    = threadIdx.x >> 6;
    int g    = lane >> 4;
    int q    = lane & 15;
    int c0   = q * 4;
    int i    = blockIdx.x * 4 + w;
    const float4 hri = *(const float4*)(hr + (size_t)i * HID + c0);
    const float4 a4  = *(const float4*)(att + c0);
    float  m = -1e30f, denom = 0.f;
    float4 acc = {0.f, 0.f, 0.f, 0.f};
    int b = rowoff[i], en = rowoff[i + 1];
    int p = b + g;
    for (; p + 4 < en; p += 8) {
        int s0 = srcs[p];
        int s1 = srcs[p + 4];
        const float4 v0 = *(const float4*)(hl + (size_t)s0 * HID + c0);
        const float4 v1 = *(const float4*)(hl + (size_t)s1 * HID + c0);
        float ex0, ey0, ez0, ew0, ex1, ey1, ez1, ew1;
        ex0 = v0.x + hri.x; ey0 = v0.y + hri.y; ez0 = v0.z + hri.z; ew0 = v0.w + hri.w;
        ex1 = v1.x + hri.x; ey1 = v1.y + hri.y; ez1 = v1.z + hri.z; ew1 = v1.w + hri.w;
        ex0 = (ex0 > 0.f) ? ex0 : 0.2f * ex0; ey0 = (ey0 > 0.f) ? ey0 : 0.2f * ey0;
        ez0 = (ez0 > 0.f) ? ez0 : 0.2f * ez0; ew0 = (ew0 > 0.f) ? ew0 : 0.2f * ew0;
        ex1 = (ex1 > 0.f) ? ex1 : 0.2f * ex1; ey1 = (ey1 > 0.f) ? ey1 : 0.2f * ey1;
        ez1 = (ez1 > 0.f) ? ez1 : 0.2f * ez1; ew1 = (ew1 > 0.f) ? ew1 : 0.2f * ew1;
        float t0 = ex0 * a4.x + ey0 * a4.y + ez0 * a4.z + ew0 * a4.w;
        float t1 = ex1 * a4.x + ey1 * a4.y + ez1 * a4.z + ew1 * a4.w;
        t0 += __shfl_xor(t0, 1); t1 += __shfl_xor(t1, 1);
        t0 += __shfl_xor(t0, 2); t1 += __shfl_xor(t1, 2);
        t0 += __shfl_xor(t0, 4); t1 += __shfl_xor(t1, 4);
        float nm = fmaxf(m, t0);
        float sc = __expf(m - nm);
        float ex = __expf(t0 - nm);
        denom = denom * sc + ex;
        acc.x = acc.x * sc + ex * v0.x;
        acc.y = acc.y * sc + ex * v0.y;
        acc.z = acc.z * sc + ex * v0.z;
        acc.w = acc.w * sc + ex * v0.w;
        m = nm;
        nm = fmaxf(m, t1);
        sc = __expf(m - nm);
        ex = __expf(t1 - nm);
        denom = denom * sc + ex;
        acc.x = acc.x * sc + ex * v1.x;
        acc.y = acc.y * sc + ex * v1.y;
        acc.z = acc.z * sc + ex * v1.z;
        acc.w = acc.w * sc + ex * v1.w;
        m = nm;
    }
    if (p < en) {
        int s = srcs[p];
        const float4 v = *(const float4*)(hl + (size_t)s * HID + c0);
        float ex0 = v.x + hri.x, ey0 = v.y + hri.y, ez0 = v.z + hri.z, ew0 = v.w + hri.w;
        ex0 = (ex0 > 0.f) ? ex0 : 0.2f * ex0; ey0 = (ey0 > 0.f) ? ey0 : 0.2f * ey0;
        ez0 = (ez0 > 0.f) ? ez0 : 0.2f * ez0; ew0 = (ew0 > 0.f) ? ew0 : 0.2f * ew0;
        float t0 = ex0 * a4.x + ey0 * a4.y + ez0 * a4.z + ew0 * a4.w;
        t0 += __shfl_xor(t0, 1);
        t0 += __shfl_xor(t0, 2);
        t0 += __shfl_xor(t0, 4);
        float nm = fmaxf(m, t0);
        float sc = __expf(m - nm);
        float ex = __expf(t0 - nm);
        denom = denom * sc + ex;
        acc.x = acc.x * sc + ex * v.x;
        acc.y = acc.y * sc + ex * v.y;
        acc.z = acc.z * sc + ex * v.z;
        acc.w = acc.w * sc + ex * v.w;
        m = nm;
    }
#pragma unroll
    for (int mask = 16; mask <= 32; mask <<= 1) {
        float m2 = __shfl_xor(m, mask);
        float d2 = __shfl_xor(denom, mask);
        float ax = __shfl_xor(acc.x, mask);
        float ay = __shfl_xor(acc.y, mask);
        float az = __shfl_xor(acc.z, mask);
        float aw = __shfl_xor(acc.w, mask);
        float nm = fmaxf(m, m2);
        float sa = __expf(m - nm);
        float sb = __expf(m2 - nm);
        denom = denom * sa + d2 * sb;
        acc.x = acc.x * sa + ax * sb;
        acc.y = acc.y * sa + ay * sb;
        acc.z = acc.z * sa + az * sb;
        acc.w = acc.w * sa + aw * sb;
        m = nm;
    }
    float inv = 1.f / (denom + 1e-16f);
    const float4 gb = *(const float4*)(gat_b + c0);
    float di = dinv[i];
    float4 o;
    o.x = fmaxf(acc.x * inv + gb.x, 0.f) * di;
    o.y = fmaxf(acc.y * inv + gb.y, 0.f) * di;
    o.z = fmaxf(acc.z * inv + gb.z, 0.f) * di;
    o.w = fmaxf(acc.w * inv + gb.w, 0.f) * di;
    if (g == 0) *(float4*)(s2 + (size_t)i * HID + c0) = o;
}

// ---------------------------------------------------------------------------
// GCN2 aggregation + transform + bias + relu + final linear, all fused.
// ---------------------------------------------------------------------------
__global__ void k_agg2_out(const int* __restrict__ rowoff, const int* __restrict__ srcs,
                           const float* __restrict__ s2, const float* __restrict__ dinv,
                           const float* __restrict__ W2, const float* __restrict__ b2,
                           const float* __restrict__ out_w, const float* __restrict__ out_b,
                           float* __restrict__ out) {
    __shared__ float lds[4][HID];
    int lane = threadIdx.x & 63;
    int w    = threadIdx.x >> 6;
    int g    = lane >> 4;
    int q    = lane & 15;
    int c0   = q * 4;
    int i    = blockIdx.x * 4 + w;
    int b = rowoff[i], en = rowoff[i + 1];
    float4 acc = {0.f, 0.f, 0.f, 0.f};
    int p = b + g;
    for (; p + 4 < en; p += 8) {
        int s0 = srcs[p];
        int s1 = srcs[p + 4];
        const float4 v0 = *(const float4*)(s2 + (size_t)s0 * HID + c0);
        const float4 v1 = *(const float4*)(s2 + (size_t)s1 * HID + c0);
        acc.x += v0.x + v1.x; acc.y += v0.y + v1.y;
        acc.z += v0.z + v1.z; acc.w += v0.w + v1.w;
    }
    if (p < en) {
        int s = srcs[p];
        const float4 v = *(const float4*)(s2 + (size_t)s * HID + c0);
        acc.x += v.x; acc.y += v.y; acc.z += v.z; acc.w += v.w;
    }
#pragma unroll
    for (int mask = 16; mask <= 32; mask <<= 1) {
        acc.x += __shfl_xor(acc.x, mask);
        acc.y += __shfl_xor(acc.y, mask);
        acc.z += __shfl_xor(acc.z, mask);
        acc.w += __shfl_xor(acc.w, mask);
    }
    if (g == 0) {
        float di = dinv[i];
        acc.x *= di; acc.y *= di; acc.z *= di; acc.w *= di;
        *(float4*)(&lds[w][c0]) = acc;
    }
    __syncthreads();
    float z = 0.f;
    const float4* row = (const float4*)lds[w];
#pragma unroll
    for (int j = 0; j < 16; ++j) {
        float4 h4 = row[j];
        z += h4.x * W2[(4 * j + 0) * HID + lane];
        z += h4.y * W2[(4 * j + 1) * HID + lane];
        z += h4.z * W2[(4 * j + 2) * HID + lane];
        z += h4.w * W2[(4 * j + 3) * HID + lane];
    }
    z = fmaxf(z + b2[lane], 0.f);
    float y = z * out_w[lane];  // out_w is (64,1) flat
    y += __shfl_xor(y, 32);
    y += __shfl_xor(y, 16);
    y += __shfl_xor(y, 8);
    y += __shfl_xor(y, 4);
    y += __shfl_xor(y, 2);
    y += __shfl_xor(y, 1);
    if (lane == 0) out[i] = y + out_b[0];
}

// ---------------------------------------------------------------------------

extern "C" void kernel_launch(void* const* d_in, const int* in_sizes, int n_in,
                              void* d_out, int out_size, void* d_ws, size_t ws_size,
                              hipStream_t stream) {
    const float* x   = (const float*)d_in[0];
    const int*   ei  = (const int*)d_in[1];
    const int*   src = ei;
    const int*   dst = ei + N_EDGES;
    const float* W1  = (const float*)d_in[2];
    const float* b1  = (const float*)d_in[3];
    const float* Wl  = (const float*)d_in[4];
    const float* Wr  = (const float*)d_in[5];
    const float* att = (const float*)d_in[6];
    const float* gb  = (const float*)d_in[7];
    const float* W2  = (const float*)d_in[8];
    const float* b2  = (const float*)d_in[9];
    const float* ow  = (const float*)d_in[10];
    const float* ob  = (const float*)d_in[11];
    float* out = (float*)d_out;

    // workspace layout (256B-aligned regions)
    char* ws = (char*)d_ws;
    size_t o = 0;
    auto alloc = [&](size_t bytes) { size_t r = o; o = (o + bytes + 255) & ~(size_t)255; return r; };
    int*   cnt     = (int*)  (ws + alloc((size_t)N_NODES * 4));
    int*   rowoff  = (int*)  (ws + alloc((size_t)(N_NODES + 1) * 4));
    int*   partial = (int*)  (ws + alloc(512 * 4));
    int*   bcnt    = (int*)  (ws + alloc((size_t)NB * 4));
    int*   boff    = (int*)  (ws + alloc((size_t)(NB + 1) * 4));
    int*   bcur    = (int*)  (ws + alloc((size_t)NB * 4));
    float* dinv    = (float*)(ws + alloc((size_t)N_NODES * 4));
    float* xs      = (float*)(ws + alloc((size_t)N_NODES * 4 * 4));
    float* aggx    = (float*)(ws + alloc((size_t)N_NODES * 4 * 4));
    int2*  binned  = (int2*) (ws + alloc((size_t)N_EDGES * 8));
    int*   srcs    = (int*)  (ws + alloc((size_t)TOT_EDGES * 4));
    float* hl      = (float*)(ws + alloc((size_t)N_NODES * HID * 4));
    float* hr      = (float*)(ws + alloc((size_t)N_NODES * HID * 4));
    float* s2      = (float*)(ws + alloc((size_t)N_NODES * HID * 4));
    (void)ws_size; (void)n_in; (void)in_sizes; (void)out_size;

    const int nbN   = (N_NODES + 255) / 256;      // 391
    const int nbW   = N_NODES / 4;                // 25000 (wave-per-node kernels, exact)
    const int nbW16 = N_NODES / 16;               // 6250  (4 nodes/wave kernels, exact)
    const int nbG   = N_NODES / 32;               // 3125  (tiled GEMM blocks, exact)

    hipMemsetAsync(bcnt, 0, (size_t)NB * 4, stream);
    k_bin_count<<<128, 1024, 0, stream>>>(dst, bcnt);
    k_bucket_scan<<<1, 512, 0, stream>>>(bcnt, boff, bcur);
    k_bin_scatter<<<128, 1024, 0, stream>>>(src, dst, bcur, binned);
    k_node_count<<<NB, 256, 0, stream>>>(binned, boff, cnt);
    k_scan1<<<nbN, 256, 0, stream>>>(cnt, partial);
    k_scan2<<<1, 512, 0, stream>>>(partial, nbN);
    k_scan3<<<nbN, 256, 0, stream>>>(cnt, partial, rowoff, dinv, x, xs);
    k_csr_scatter<<<NB, 256, 0, stream>>>(binned, boff, rowoff, srcs);
    k_agg_x<<<nbW16, 256, 0, stream>>>(rowoff, srcs, xs, dinv, aggx);
    k_hlhr<<<nbG, 256, 0, stream>>>(aggx, W1, b1, Wl, Wr, hl, hr);
    k_gat<<<nbW, 256, 0, stream>>>(rowoff, srcs, hl, hr, att, gb, dinv, s2);
    k_agg2_out<<<nbW, 256, 0, stream>>>(rowoff, srcs, s2, dinv, W2, b2, ow, ob, out);
}

// Round 6
// 256.935 us; speedup vs baseline: 2.7860x; 1.0779x over previous
//
#include <hip/hip_runtime.h>
#include <math.h>

// Problem constants (match reference file)
#define N_NODES 100000
#define N_EDGES 1600000
#define HID 64
#define NB 391        // node buckets of 256 nodes (100000>>8 -> 0..390)
#define CAP 4608      // bucket edge capacity: mean 4092, sigma~64 -> +8 sigma
#define SCAP (CAP + 256)  // srcs region per bucket (edges + self-loops)

// ---------------------------------------------------------------------------
// One-pass bucketed edge scatter. Packed entry: src | (dst&255)<<24.
// Per-block LDS histogram -> one global reservation per (block,bucket) ->
// scatter into fixed-capacity bucket regions.
// ---------------------------------------------------------------------------
__global__ void k_bin_scatter(const int* __restrict__ src, const int* __restrict__ dst,
                              int* __restrict__ gcur, unsigned int* __restrict__ binned) {
    __shared__ int hist[NB];
    __shared__ int base[NB];
    for (int t = threadIdx.x; t < NB; t += blockDim.x) hist[t] = 0;
    __syncthreads();
    int stride = gridDim.x * blockDim.x;
    int gid = blockIdx.x * blockDim.x + threadIdx.x;
    for (int e = gid; e < N_EDGES; e += stride)
        atomicAdd(&hist[dst[e] >> 8], 1);
    __syncthreads();
    for (int t = threadIdx.x; t < NB; t += blockDim.x) {
        int h = hist[t];
        base[t] = h ? atomicAdd(&gcur[t], h) : 0;
        hist[t] = 0;
    }
    __syncthreads();
    for (int e = gid; e < N_EDGES; e += stride) {
        int d = dst[e];
        int bkt = d >> 8;
        int off = base[bkt] + atomicAdd(&hist[bkt], 1);
        binned[(size_t)bkt * CAP + off] = (unsigned int)src[e] | ((unsigned int)(d & 255) << 24);
    }
}

// ---------------------------------------------------------------------------
// Per-bucket: count -> scan -> node meta (rowbeg/rowend/dinv/xs) -> CSR
// scatter (from LDS stash). One block per bucket, 256 threads.
// ---------------------------------------------------------------------------
__global__ void __launch_bounds__(256) k_node_scan(
        const unsigned int* __restrict__ binned, const int* __restrict__ gcur,
        const float* __restrict__ x, int* __restrict__ rowbeg, int* __restrict__ rowend,
        float* __restrict__ dinv, float* __restrict__ xs, int* __restrict__ srcs) {
    __shared__ unsigned int stash[CAP];
    __shared__ int c[256];
    __shared__ int scan[256];
    int b = blockIdx.x, t = threadIdx.x;
    int n0 = b << 8;
    int ne = gcur[b];
    c[t] = 1;  // self-loop
    __syncthreads();
    for (int i = t; i < ne; i += 256) {
        unsigned int v = binned[(size_t)b * CAP + i];
        stash[i] = v;
        atomicAdd(&c[v >> 24], 1);
    }
    __syncthreads();
    int cnt = c[t];
    scan[t] = cnt;
    __syncthreads();
    for (int off = 1; off < 256; off <<= 1) {
        int add = (t >= off) ? scan[t - off] : 0;
        __syncthreads();
        scan[t] += add;
        __syncthreads();
    }
    int rb = b * SCAP + (scan[t] - cnt);  // exclusive, bucket-local srcs region
    int gn = n0 + t;
    if (gn < N_NODES) {
        rowbeg[gn] = rb;
        rowend[gn] = rb + cnt;
        float di = rsqrtf((float)cnt);
        dinv[gn] = di;
        float4 xv = ((const float4*)x)[gn];
        xv.x *= di; xv.y *= di; xv.z *= di; xv.w *= di;
        ((float4*)xs)[gn] = xv;
    }
    __syncthreads();
    c[t] = rb;  // cursors
    __syncthreads();
    for (int i = t; i < ne; i += 256) {
        unsigned int v = stash[i];
        int pos = atomicAdd(&c[v >> 24], 1);
        srcs[pos] = (int)(v & 0xFFFFFFu);
    }
    __syncthreads();
    if (gn < N_NODES) srcs[c[t]] = gn;  // self-loop in last slot
}

// ---------------------------------------------------------------------------
// Fused: GCN1 aggregation (4-ch gather) -> h1 = relu(aggx@W1+b1) ->
// hl = h1@Wl, hr = h1@Wr.  Block = 256 threads = 32 nodes (3125 blocks, exact).
// Part A: 16-lane group g gathers nodes 2g,2g+1 (float4/edge) -> LDS.
// Part B: h1 tile [32][64] in LDS.
// Part C: register-tiled GEMM, 8 nodes/thread, k-chunks of 4 (no spills).
// ---------------------------------------------------------------------------
__global__ void __launch_bounds__(256) k_aggx_hlhr(
        const int* __restrict__ rowbeg, const int* __restrict__ rowend,
        const int* __restrict__ srcs, const float* __restrict__ xs,
        const float* __restrict__ dinv, const float* __restrict__ W1,
        const float* __restrict__ b1, const float* __restrict__ Wl,
        const float* __restrict__ Wr, float* __restrict__ hl,
        float* __restrict__ hr) {
    __shared__ float4 aggx_t[32];
    __shared__ float h1[32 * HID];
    int lane = threadIdx.x & 63;
    int w    = threadIdx.x >> 6;
    int g    = threadIdx.x >> 4;   // 16-lane group (0..15), contained in a wave
    int q    = threadIdx.x & 15;
    int n0   = blockIdx.x * 32;
    // part A: gather
#pragma unroll
    for (int k = 0; k < 2; ++k) {
        int n = g * 2 + k;
        int i = n0 + n;
        int rb = rowbeg[i], re = rowend[i];
        float4 acc = {0.f, 0.f, 0.f, 0.f};
        for (int p = rb + q; p < re; p += 16) {
            float4 v = ((const float4*)xs)[srcs[p]];
            acc.x += v.x; acc.y += v.y; acc.z += v.z; acc.w += v.w;
        }
#pragma unroll
        for (int mask = 1; mask <= 8; mask <<= 1) {
            acc.x += __shfl_xor(acc.x, mask);
            acc.y += __shfl_xor(acc.y, mask);
            acc.z += __shfl_xor(acc.z, mask);
            acc.w += __shfl_xor(acc.w, mask);
        }
        if (q == 0) {
            float di = dinv[i];
            acc.x *= di; acc.y *= di; acc.z *= di; acc.w *= di;
            aggx_t[n] = acc;
        }
    }
    __syncthreads();
    // part B: h1 tile (wave w computes rows w*8 .. w*8+7)
    float w10 = W1[0 * HID + lane], w11 = W1[1 * HID + lane];
    float w12 = W1[2 * HID + lane], w13 = W1[3 * HID + lane];
    float bb  = b1[lane];
#pragma unroll
    for (int j = 0; j < 8; ++j) {
        int n = w * 8 + j;
        float4 a = aggx_t[n];
        h1[n * HID + lane] = fmaxf(a.x * w10 + a.y * w11 + a.z * w12 + a.w * w13 + bb, 0.f);
    }
    __syncthreads();
    // part C: 8 nodes per thread, k in chunks of 4
    float al[8], ar[8];
#pragma unroll
    for (int j = 0; j < 8; ++j) { al[j] = 0.f; ar[j] = 0.f; }
#pragma unroll 2
    for (int k0 = 0; k0 < 16; ++k0) {
        float wl0 = Wl[(k0 * 4 + 0) * HID + lane];
        float wl1 = Wl[(k0 * 4 + 1) * HID + lane];
        float wl2 = Wl[(k0 * 4 + 2) * HID + lane];
        float wl3 = Wl[(k0 * 4 + 3) * HID + lane];
        float wr0 = Wr[(k0 * 4 + 0) * HID + lane];
        float wr1 = Wr[(k0 * 4 + 1) * HID + lane];
        float wr2 = Wr[(k0 * 4 + 2) * HID + lane];
        float wr3 = Wr[(k0 * 4 + 3) * HID + lane];
#pragma unroll
        for (int j = 0; j < 8; ++j) {
            const float4 hv = *(const float4*)(&h1[(w * 8 + j) * HID + k0 * 4]);
            al[j] += hv.x * wl0 + hv.y * wl1 + hv.z * wl2 + hv.w * wl3;
            ar[j] += hv.x * wr0 + hv.y * wr1 + hv.z * wr2 + hv.w * wr3;
        }
    }
#pragma unroll
    for (int j = 0; j < 8; ++j) {
        int gn = n0 + w * 8 + j;
        hl[(size_t)gn * HID + lane] = al[j];
        hr[(size_t)gn * HID + lane] = ar[j];
    }
}

// ---------------------------------------------------------------------------
// GATv2 online softmax, 2x unrolled: 8 row-gathers in flight per wave.
// ---------------------------------------------------------------------------
__global__ void k_gat(const int* __restrict__ rowbeg, const int* __restrict__ rowend,
                      const int* __restrict__ srcs,
                      const float* __restrict__ hl, const float* __restrict__ hr,
                      const float* __restrict__ att, const float* __restrict__ gat_b,
                      const float* __restrict__ dinv, float* __restrict__ s2) {
    int lane = threadIdx.x & 63;
    int w    = threadIdx.x >> 6;
    int g    = lane >> 4;
    int q    = lane & 15;
    int c0   = q * 4;
    int i    = blockIdx.x * 4 + w;
    const float4 hri = *(const float4*)(hr + (size_t)i * HID + c0);
    const float4 a4  = *(const float4*)(att + c0);
    float  m = -1e30f, denom = 0.f;
    float4 acc = {0.f, 0.f, 0.f, 0.f};
    int b = rowbeg[i], en = rowend[i];
    int p = b + g;
    for (; p + 4 < en; p += 8) {
        int s0 = srcs[p];
        int s1 = srcs[p + 4];
        const float4 v0 = *(const float4*)(hl + (size_t)s0 * HID + c0);
        const float4 v1 = *(const float4*)(hl + (size_t)s1 * HID + c0);
        float ex0, ey0, ez0, ew0, ex1, ey1, ez1, ew1;
        ex0 = v0.x + hri.x; ey0 = v0.y + hri.y; ez0 = v0.z + hri.z; ew0 = v0.w + hri.w;
        ex1 = v1.x + hri.x; ey1 = v1.y + hri.y; ez1 = v1.z + hri.z; ew1 = v1.w + hri.w;
        ex0 = (ex0 > 0.f) ? ex0 : 0.2f * ex0; ey0 = (ey0 > 0.f) ? ey0 : 0.2f * ey0;
        ez0 = (ez0 > 0.f) ? ez0 : 0.2f * ez0; ew0 = (ew0 > 0.f) ? ew0 : 0.2f * ew0;
        ex1 = (ex1 > 0.f) ? ex1 : 0.2f * ex1; ey1 = (ey1 > 0.f) ? ey1 : 0.2f * ey1;
        ez1 = (ez1 > 0.f) ? ez1 : 0.2f * ez1; ew1 = (ew1 > 0.f) ? ew1 : 0.2f * ew1;
        float t0 = ex0 * a4.x + ey0 * a4.y + ez0 * a4.z + ew0 * a4.w;
        float t1 = ex1 * a4.x + ey1 * a4.y + ez1 * a4.z + ew1 * a4.w;
        t0 += __shfl_xor(t0, 1); t1 += __shfl_xor(t1, 1);
        t0 += __shfl_xor(t0, 2); t1 += __shfl_xor(t1, 2);
        t0 += __shfl_xor(t0, 4); t1 += __shfl_xor(t1, 4);
        float nm = fmaxf(m, t0);
        float sc = __expf(m - nm);
        float ex = __expf(t0 - nm);
        denom = denom * sc + ex;
        acc.x = acc.x * sc + ex * v0.x;
        acc.y = acc.y * sc + ex * v0.y;
        acc.z = acc.z * sc + ex * v0.z;
        acc.w = acc.w * sc + ex * v0.w;
        m = nm;
        nm = fmaxf(m, t1);
        sc = __expf(m - nm);
        ex = __expf(t1 - nm);
        denom = denom * sc + ex;
        acc.x = acc.x * sc + ex * v1.x;
        acc.y = acc.y * sc + ex * v1.y;
        acc.z = acc.z * sc + ex * v1.z;
        acc.w = acc.w * sc + ex * v1.w;
        m = nm;
    }
    if (p < en) {
        int s = srcs[p];
        const float4 v = *(const float4*)(hl + (size_t)s * HID + c0);
        float ex0 = v.x + hri.x, ey0 = v.y + hri.y, ez0 = v.z + hri.z, ew0 = v.w + hri.w;
        ex0 = (ex0 > 0.f) ? ex0 : 0.2f * ex0; ey0 = (ey0 > 0.f) ? ey0 : 0.2f * ey0;
        ez0 = (ez0 > 0.f) ? ez0 : 0.2f * ez0; ew0 = (ew0 > 0.f) ? ew0 : 0.2f * ew0;
        float t0 = ex0 * a4.x + ey0 * a4.y + ez0 * a4.z + ew0 * a4.w;
        t0 += __shfl_xor(t0, 1);
        t0 += __shfl_xor(t0, 2);
        t0 += __shfl_xor(t0, 4);
        float nm = fmaxf(m, t0);
        float sc = __expf(m - nm);
        float ex = __expf(t0 - nm);
        denom = denom * sc + ex;
        acc.x = acc.x * sc + ex * v.x;
        acc.y = acc.y * sc + ex * v.y;
        acc.z = acc.z * sc + ex * v.z;
        acc.w = acc.w * sc + ex * v.w;
        m = nm;
    }
#pragma unroll
    for (int mask = 16; mask <= 32; mask <<= 1) {
        float m2 = __shfl_xor(m, mask);
        float d2 = __shfl_xor(denom, mask);
        float ax = __shfl_xor(acc.x, mask);
        float ay = __shfl_xor(acc.y, mask);
        float az = __shfl_xor(acc.z, mask);
        float aw = __shfl_xor(acc.w, mask);
        float nm = fmaxf(m, m2);
        float sa = __expf(m - nm);
        float sb = __expf(m2 - nm);
        denom = denom * sa + d2 * sb;
        acc.x = acc.x * sa + ax * sb;
        acc.y = acc.y * sa + ay * sb;
        acc.z = acc.z * sa + az * sb;
        acc.w = acc.w * sa + aw * sb;
        m = nm;
    }
    float inv = 1.f / (denom + 1e-16f);
    const float4 gb = *(const float4*)(gat_b + c0);
    float di = dinv[i];
    float4 o;
    o.x = fmaxf(acc.x * inv + gb.x, 0.f) * di;
    o.y = fmaxf(acc.y * inv + gb.y, 0.f) * di;
    o.z = fmaxf(acc.z * inv + gb.z, 0.f) * di;
    o.w = fmaxf(acc.w * inv + gb.w, 0.f) * di;
    if (g == 0) *(float4*)(s2 + (size_t)i * HID + c0) = o;
}

// ---------------------------------------------------------------------------
// GCN2 aggregation + transform + bias + relu + final linear, all fused.
// ---------------------------------------------------------------------------
__global__ void k_agg2_out(const int* __restrict__ rowbeg, const int* __restrict__ rowend,
                           const int* __restrict__ srcs,
                           const float* __restrict__ s2, const float* __restrict__ dinv,
                           const float* __restrict__ W2, const float* __restrict__ b2,
                           const float* __restrict__ out_w, const float* __restrict__ out_b,
                           float* __restrict__ out) {
    __shared__ float lds[4][HID];
    int lane = threadIdx.x & 63;
    int w    = threadIdx.x >> 6;
    int g    = lane >> 4;
    int q    = lane & 15;
    int c0   = q * 4;
    int i    = blockIdx.x * 4 + w;
    int b = rowbeg[i], en = rowend[i];
    float4 acc = {0.f, 0.f, 0.f, 0.f};
    int p = b + g;
    for (; p + 4 < en; p += 8) {
        int s0 = srcs[p];
        int s1 = srcs[p + 4];
        const float4 v0 = *(const float4*)(s2 + (size_t)s0 * HID + c0);
        const float4 v1 = *(const float4*)(s2 + (size_t)s1 * HID + c0);
        acc.x += v0.x + v1.x; acc.y += v0.y + v1.y;
        acc.z += v0.z + v1.z; acc.w += v0.w + v1.w;
    }
    if (p < en) {
        int s = srcs[p];
        const float4 v = *(const float4*)(s2 + (size_t)s * HID + c0);
        acc.x += v.x; acc.y += v.y; acc.z += v.z; acc.w += v.w;
    }
#pragma unroll
    for (int mask = 16; mask <= 32; mask <<= 1) {
        acc.x += __shfl_xor(acc.x, mask);
        acc.y += __shfl_xor(acc.y, mask);
        acc.z += __shfl_xor(acc.z, mask);
        acc.w += __shfl_xor(acc.w, mask);
    }
    if (g == 0) {
        float di = dinv[i];
        acc.x *= di; acc.y *= di; acc.z *= di; acc.w *= di;
        *(float4*)(&lds[w][c0]) = acc;
    }
    __syncthreads();
    float z = 0.f;
    const float4* row = (const float4*)lds[w];
#pragma unroll
    for (int j = 0; j < 16; ++j) {
        float4 h4 = row[j];
        z += h4.x * W2[(4 * j + 0) * HID + lane];
        z += h4.y * W2[(4 * j + 1) * HID + lane];
        z += h4.z * W2[(4 * j + 2) * HID + lane];
        z += h4.w * W2[(4 * j + 3) * HID + lane];
    }
    z = fmaxf(z + b2[lane], 0.f);
    float y = z * out_w[lane];  // out_w is (64,1) flat
    y += __shfl_xor(y, 32);
    y += __shfl_xor(y, 16);
    y += __shfl_xor(y, 8);
    y += __shfl_xor(y, 4);
    y += __shfl_xor(y, 2);
    y += __shfl_xor(y, 1);
    if (lane == 0) out[i] = y + out_b[0];
}

// ---------------------------------------------------------------------------

extern "C" void kernel_launch(void* const* d_in, const int* in_sizes, int n_in,
                              void* d_out, int out_size, void* d_ws, size_t ws_size,
                              hipStream_t stream) {
    const float* x   = (const float*)d_in[0];
    const int*   ei  = (const int*)d_in[1];
    const int*   src = ei;
    const int*   dst = ei + N_EDGES;
    const float* W1  = (const float*)d_in[2];
    const float* b1  = (const float*)d_in[3];
    const float* Wl  = (const float*)d_in[4];
    const float* Wr  = (const float*)d_in[5];
    const float* att = (const float*)d_in[6];
    const float* gb  = (const float*)d_in[7];
    const float* W2  = (const float*)d_in[8];
    const float* b2  = (const float*)d_in[9];
    const float* ow  = (const float*)d_in[10];
    const float* ob  = (const float*)d_in[11];
    float* out = (float*)d_out;

    // workspace layout (256B-aligned regions)
    char* ws = (char*)d_ws;
    size_t o = 0;
    auto alloc = [&](size_t bytes) { size_t r = o; o = (o + bytes + 255) & ~(size_t)255; return r; };
    int*          gcur   = (int*)         (ws + alloc((size_t)NB * 4));
    unsigned int* binned = (unsigned int*)(ws + alloc((size_t)NB * CAP * 4));
    int*          srcs   = (int*)         (ws + alloc((size_t)NB * SCAP * 4));
    int*          rowbeg = (int*)         (ws + alloc((size_t)N_NODES * 4));
    int*          rowend = (int*)         (ws + alloc((size_t)N_NODES * 4));
    float*        dinv   = (float*)       (ws + alloc((size_t)N_NODES * 4));
    float*        xs     = (float*)       (ws + alloc((size_t)N_NODES * 4 * 4));
    float*        hl     = (float*)       (ws + alloc((size_t)N_NODES * HID * 4));
    float*        hr     = (float*)       (ws + alloc((size_t)N_NODES * HID * 4));
    float*        s2     = (float*)       (ws + alloc((size_t)N_NODES * HID * 4));
    (void)ws_size; (void)n_in; (void)in_sizes; (void)out_size;

    const int nbW   = N_NODES / 4;        // 25000 (wave-per-node kernels, exact)
    const int nbG   = N_NODES / 32;       // 3125  (fused gather+GEMM blocks, exact)

    hipMemsetAsync(gcur, 0, (size_t)NB * 4, stream);
    k_bin_scatter<<<128, 1024, 0, stream>>>(src, dst, gcur, binned);
    k_node_scan<<<NB, 256, 0, stream>>>(binned, gcur, x, rowbeg, rowend, dinv, xs, srcs);
    k_aggx_hlhr<<<nbG, 256, 0, stream>>>(rowbeg, rowend, srcs, xs, dinv, W1, b1, Wl, Wr, hl, hr);
    k_gat<<<nbW, 256, 0, stream>>>(rowbeg, rowend, srcs, hl, hr, att, gb, dinv, s2);
    k_agg2_out<<<nbW, 256, 0, stream>>>(rowbeg, rowend, srcs, s2, dinv, W2, b2, ow, ob, out);
}